// Round 2
// baseline (785.174 us; speedup 1.0000x reference)
//
#include <hip/hip_runtime.h>
#include <hip/hip_fp16.h>
#include <math.h>

// Problem constants (setup_inputs fixed: 1x3x2048x2048 fp32)
#define HH    2048
#define WW    2048
#define NCH   3
#define NOUT  2038          // 2048 - 10 (VALID 11-tap twice)
#define OWID  64            // output tile width
#define OHGT  32            // output tile height
#define IHGT  42            // OHGT + 10 (h-blurred rows needed)
#define SH    68            // padded LDS row stride in halves (136B: 8B-aligned, ≡2 banks mod 32)
#define NTX   32            // ceil(2038/64)
#define NTY   64            // ceil(2038/32)
#define NBLOCKS (NTX*NTY*NCH)
#define NOUT_TOTAL 12460332.0f   // 3 * 2038 * 2038

__global__ __launch_bounds__(256, 4)
void ssim_main(const float* __restrict__ x, const float* __restrict__ y,
               float* __restrict__ acc, unsigned int* __restrict__ cnt,
               float* __restrict__ out) {
    // 5 h-blurred quantities (mu1,mu2,xx,yy,xy) in fp16: 5*42*68*2 = 28.6 KB
    __shared__ __half hb[5][IHGT][SH];
    __shared__ float wsum[4];

    const int tid = threadIdx.x;
    const int gx0 = blockIdx.x * OWID;
    const int gy0 = blockIdx.y * OHGT;
    const float* xb = x + (size_t)blockIdx.z * HH * WW;
    const float* yb = y + (size_t)blockIdx.z * HH * WW;

    // Gaussian weights (11 taps, sigma 1.5), normalized — matches jnp f32
    float w[11];
    {
        float s = 0.f;
        #pragma unroll
        for (int i = 0; i < 11; ++i) {
            float d = (float)(i - 5);
            w[i] = expf(-d * d / 4.5f);
            s += w[i];
        }
        float inv = 1.f / s;
        #pragma unroll
        for (int i = 0; i < 11; ++i) w[i] *= inv;
    }

    // ---- Stage B: horizontal blur, reading input windows straight from
    // global (float4; same-wave 4x overlap hits L1). Unit = (row, 4 cols). ----
    for (int u = tid; u < IHGT * (OWID / 4); u += 256) {
        int r  = u >> 4;
        int c0 = (u & 15) * 4;
        int gy = gy0 + r; if (gy > HH - 1) gy = HH - 1;
        const float* xr = xb + (size_t)gy * WW;
        const float* yr = yb + (size_t)gy * WW;
        int gxc = gx0 + c0;

        float4 xv4[4], yv4[4];
        if (gxc + 16 <= WW) {
            #pragma unroll
            for (int t = 0; t < 4; ++t) {
                xv4[t] = *(const float4*)(xr + gxc + 4 * t);
                yv4[t] = *(const float4*)(yr + gxc + 4 * t);
            }
        } else {  // right-edge clamp (only last block column; clamped values
                  // feed only guarded outputs)
            float* xs = (float*)xv4; float* ys = (float*)yv4;
            #pragma unroll
            for (int t = 0; t < 16; ++t) {
                int gc = gxc + t; if (gc > WW - 1) gc = WW - 1;
                xs[t] = xr[gc]; ys[t] = yr[gc];
            }
        }
        const float* xv = (const float*)xv4;
        const float* yv = (const float*)yv4;

        float xx[14], yy2[14], xy[14];
        #pragma unroll
        for (int t = 0; t < 14; ++t) {
            xx[t]  = xv[t] * xv[t];
            yy2[t] = yv[t] * yv[t];
            xy[t]  = xv[t] * yv[t];
        }
        float h[5][4] = {};
        #pragma unroll
        for (int k = 0; k < 11; ++k) {
            #pragma unroll
            for (int j = 0; j < 4; ++j) {
                h[0][j] = fmaf(w[k], xv[j + k],  h[0][j]);
                h[1][j] = fmaf(w[k], yv[j + k],  h[1][j]);
                h[2][j] = fmaf(w[k], xx[j + k],  h[2][j]);
                h[3][j] = fmaf(w[k], yy2[j + k], h[3][j]);
                h[4][j] = fmaf(w[k], xy[j + k],  h[4][j]);
            }
        }
        #pragma unroll
        for (int q = 0; q < 5; ++q) {
            *(__half2*)&hb[q][r][c0]     = __floats2half2_rn(h[q][0], h[q][1]);
            *(__half2*)&hb[q][r][c0 + 2] = __floats2half2_rn(h[q][2], h[q][3]);
        }
    }
    __syncthreads();

    // ---- Stage C: vertical blur, 4 cols x 2 rows per thread (b64 LDS reads,
    // 12-row window shared between the two output rows) + SSIM + partial sum ----
    float partial = 0.f;
    {
        const int c0 = (tid & 15) * 4;
        const int r0 = (tid >> 4) * 2;
        const __half* hp = &hb[0][r0][c0];
        float a0[5][4] = {}, a1[5][4] = {};
        #pragma unroll
        for (int j = 0; j < 12; ++j) {
            float v[5][4];
            #pragma unroll
            for (int q = 0; q < 5; ++q) {
                const __half* p = hp + q * (IHGT * SH) + j * SH;
                float2 lo = __half22float2(*(const __half2*)p);
                float2 hi = __half22float2(*(const __half2*)(p + 2));
                v[q][0] = lo.x; v[q][1] = lo.y; v[q][2] = hi.x; v[q][3] = hi.y;
            }
            if (j < 11) {
                #pragma unroll
                for (int q = 0; q < 5; ++q)
                    #pragma unroll
                    for (int c = 0; c < 4; ++c)
                        a0[q][c] = fmaf(w[j], v[q][c], a0[q][c]);
            }
            if (j >= 1) {
                #pragma unroll
                for (int q = 0; q < 5; ++q)
                    #pragma unroll
                    for (int c = 0; c < 4; ++c)
                        a1[q][c] = fmaf(w[j - 1], v[q][c], a1[q][c]);
            }
        }
        const float c1v = 1e-4f, c2v = 9e-4f;
        #pragma unroll
        for (int i = 0; i < 2; ++i) {
            int orow = gy0 + r0 + i;
            if (orow < NOUT) {
                float (*A)[4] = i ? a1 : a0;
                #pragma unroll
                for (int c = 0; c < 4; ++c) {
                    int ocol = gx0 + c0 + c;
                    if (ocol < NOUT) {
                        float mu1 = A[0][c], mu2 = A[1][c];
                        float b11 = A[2][c], b22 = A[3][c], b12 = A[4][c];
                        float mu1sq = mu1 * mu1;
                        float mu2sq = mu2 * mu2;
                        float mu12  = mu1 * mu2;
                        float s11 = b11 - mu1sq;
                        float s22 = b22 - mu2sq;
                        float s12 = b12 - mu12;
                        float csn = 2.f * s12 + c2v;
                        float csd = s11 + s22 + c2v;
                        float ln  = 2.f * mu12 + c1v;
                        float ld  = mu1sq + mu2sq + c1v;
                        partial += (csn * ln) / (csd * ld);
                    }
                }
            }
        }
    }

    // ---- Reduction: wave shuffle -> block -> one atomic; last block finalizes ----
    #pragma unroll
    for (int off = 32; off > 0; off >>= 1)
        partial += __shfl_down(partial, off, 64);
    if ((tid & 63) == 0) wsum[tid >> 6] = partial;
    __syncthreads();
    if (tid == 0) {
        float s = wsum[0] + wsum[1] + wsum[2] + wsum[3];
        atomicAdd(acc, s);
        __threadfence();
        unsigned t = atomicAdd(cnt, 1u);
        if (t == (unsigned)(NBLOCKS - 1)) {
            float tot = atomicAdd(acc, 0.0f);  // atomic read of final total
            out[0] = 1.0f - tot / NOUT_TOTAL;
        }
    }
}

extern "C" void kernel_launch(void* const* d_in, const int* in_sizes, int n_in,
                              void* d_out, int out_size, void* d_ws, size_t ws_size,
                              hipStream_t stream) {
    const float* x = (const float*)d_in[0];
    const float* y = (const float*)d_in[1];
    float* out = (float*)d_out;
    float* acc = (float*)d_ws;                 // ws[0]: f32 accumulator
    unsigned int* cnt = (unsigned int*)d_ws + 1;  // ws[1]: block ticket counter

    // d_ws is re-poisoned (0xAA) before every launch — zero acc + counter.
    hipMemsetAsync(d_ws, 0, 8, stream);

    dim3 grid(NTX, NTY, NCH);
    ssim_main<<<grid, dim3(256), 0, stream>>>(x, y, acc, cnt, out);
}

// Round 3
// 646.199 us; speedup vs baseline: 1.2151x; 1.2151x over previous
//
#include <hip/hip_runtime.h>
#include <hip/hip_fp16.h>
#include <math.h>

// Problem constants (setup_inputs fixed: 1x3x2048x2048 fp32)
#define HH    2048
#define WW    2048
#define NCH   3
#define NOUT  2038          // 2048 - 10 (VALID 11-tap twice)
#define OWID  64            // output tile width
#define OHGT  32            // output tile height
#define IHGT  42            // OHGT + 10 (h-blurred rows needed)
#define SH    72            // LDS row stride in halves: 144B = 8B-aligned rows, ≡4 banks mod 32
#define NTX   32            // ceil(2038/64)
#define NTY   64            // ceil(2038/32)
#define NBLOCKS (NTX*NTY*NCH)
#define NOUT_TOTAL 12460332.0f   // 3 * 2038 * 2038

// SSIM per-pixel term from the 5 blurred quantities. Scalar args only —
// callers must use compile-time array indices (NO runtime pointer selection
// of register arrays: that demoted a0/a1 to scratch in round 2 → 664 MB of
// spill writes, 712 us).
__device__ __forceinline__ float ssim_term(float mu1, float mu2,
                                           float b11, float b22, float b12) {
    const float c1v = 1e-4f, c2v = 9e-4f;
    float mu1sq = mu1 * mu1;
    float mu2sq = mu2 * mu2;
    float mu12  = mu1 * mu2;
    float s11 = b11 - mu1sq;
    float s22 = b22 - mu2sq;
    float s12 = b12 - mu12;
    float csn = 2.f * s12 + c2v;
    float csd = s11 + s22 + c2v;
    float ln  = 2.f * mu12 + c1v;
    float ld  = mu1sq + mu2sq + c1v;
    return (csn * ln) / (csd * ld);
}

__global__ __launch_bounds__(256, 4)
void ssim_main(const float* __restrict__ x, const float* __restrict__ y,
               float* __restrict__ acc, unsigned int* __restrict__ cnt,
               float* __restrict__ out) {
    // 5 h-blurred quantities (mu1,mu2,xx,yy,xy) in fp16: 5*42*72*2 = 30.2 KB
    __shared__ __half hb[5][IHGT][SH];
    __shared__ float wsum[4];

    const int tid = threadIdx.x;
    const int gx0 = blockIdx.x * OWID;
    const int gy0 = blockIdx.y * OHGT;
    const float* xb = x + (size_t)blockIdx.z * HH * WW;
    const float* yb = y + (size_t)blockIdx.z * HH * WW;

    // Gaussian weights (11 taps, sigma 1.5), normalized — matches jnp f32
    float w[11];
    {
        float s = 0.f;
        #pragma unroll
        for (int i = 0; i < 11; ++i) {
            float d = (float)(i - 5);
            w[i] = expf(-d * d / 4.5f);
            s += w[i];
        }
        float inv = 1.f / s;
        #pragma unroll
        for (int i = 0; i < 11; ++i) w[i] *= inv;
    }

    // ---- Stage B: horizontal blur, reading input windows straight from
    // global (float4; same-wave 4x overlap hits L1). Unit = (row, 4 cols). ----
    for (int u = tid; u < IHGT * (OWID / 4); u += 256) {
        int r  = u >> 4;
        int c0 = (u & 15) * 4;
        int gy = gy0 + r; if (gy > HH - 1) gy = HH - 1;
        const float* xr = xb + (size_t)gy * WW;
        const float* yr = yb + (size_t)gy * WW;
        int gxc = gx0 + c0;

        float4 xv4[4], yv4[4];
        if (gxc + 16 <= WW) {
            #pragma unroll
            for (int t = 0; t < 4; ++t) {
                xv4[t] = *(const float4*)(xr + gxc + 4 * t);
                yv4[t] = *(const float4*)(yr + gxc + 4 * t);
            }
        } else {  // right-edge clamp (last block column only; clamped values
                  // feed only guarded outputs)
            float* xs = (float*)xv4; float* ys = (float*)yv4;
            #pragma unroll
            for (int t = 0; t < 16; ++t) {
                int gc = gxc + t; if (gc > WW - 1) gc = WW - 1;
                xs[t] = xr[gc]; ys[t] = yr[gc];
            }
        }
        const float* xv = (const float*)xv4;
        const float* yv = (const float*)yv4;

        float xx[14], yy2[14], xy[14];
        #pragma unroll
        for (int t = 0; t < 14; ++t) {
            xx[t]  = xv[t] * xv[t];
            yy2[t] = yv[t] * yv[t];
            xy[t]  = xv[t] * yv[t];
        }
        float h[5][4] = {};
        #pragma unroll
        for (int k = 0; k < 11; ++k) {
            #pragma unroll
            for (int j = 0; j < 4; ++j) {
                h[0][j] = fmaf(w[k], xv[j + k],  h[0][j]);
                h[1][j] = fmaf(w[k], yv[j + k],  h[1][j]);
                h[2][j] = fmaf(w[k], xx[j + k],  h[2][j]);
                h[3][j] = fmaf(w[k], yy2[j + k], h[3][j]);
                h[4][j] = fmaf(w[k], xy[j + k],  h[4][j]);
            }
        }
        #pragma unroll
        for (int q = 0; q < 5; ++q) {
            // 8B-aligned (SH*2=144B rows, c0*2 multiple of 8) -> ds_write_b64
            *(__half2*)&hb[q][r][c0]     = __floats2half2_rn(h[q][0], h[q][1]);
            *(__half2*)&hb[q][r][c0 + 2] = __floats2half2_rn(h[q][2], h[q][3]);
        }
    }
    __syncthreads();

    // ---- Stage C: vertical blur, 4 cols x 2 rows per thread (ds_read_b64,
    // 12-row window shared between the two output rows) + SSIM + partial sum ----
    float partial = 0.f;
    {
        const int c0 = (tid & 15) * 4;
        const int r0 = (tid >> 4) * 2;
        const __half* hp = &hb[0][r0][c0];
        float a0[5][4] = {}, a1[5][4] = {};
        #pragma unroll
        for (int j = 0; j < 12; ++j) {
            float v[5][4];
            #pragma unroll
            for (int q = 0; q < 5; ++q) {
                const __half* p = hp + q * (IHGT * SH) + j * SH;
                float2 raw = *(const float2*)p;          // one ds_read_b64
                float2 lo = __half22float2(*(const __half2*)&raw.x);
                float2 hi = __half22float2(*(const __half2*)&raw.y);
                v[q][0] = lo.x; v[q][1] = lo.y; v[q][2] = hi.x; v[q][3] = hi.y;
            }
            if (j < 11) {
                #pragma unroll
                for (int q = 0; q < 5; ++q)
                    #pragma unroll
                    for (int c = 0; c < 4; ++c)
                        a0[q][c] = fmaf(w[j], v[q][c], a0[q][c]);
            }
            if (j >= 1) {
                #pragma unroll
                for (int q = 0; q < 5; ++q)
                    #pragma unroll
                    for (int c = 0; c < 4; ++c)
                        a1[q][c] = fmaf(w[j - 1], v[q][c], a1[q][c]);
            }
        }
        const bool row0ok = (gy0 + r0)     < NOUT;
        const bool row1ok = (gy0 + r0 + 1) < NOUT;
        #pragma unroll
        for (int c = 0; c < 4; ++c) {
            bool colok = (gx0 + c0 + c) < NOUT;
            if (row0ok && colok)
                partial += ssim_term(a0[0][c], a0[1][c], a0[2][c], a0[3][c], a0[4][c]);
            if (row1ok && colok)
                partial += ssim_term(a1[0][c], a1[1][c], a1[2][c], a1[3][c], a1[4][c]);
        }
    }

    // ---- Reduction: wave shuffle -> block -> one atomic; last block finalizes ----
    #pragma unroll
    for (int off = 32; off > 0; off >>= 1)
        partial += __shfl_down(partial, off, 64);
    if ((tid & 63) == 0) wsum[tid >> 6] = partial;
    __syncthreads();
    if (tid == 0) {
        float s = wsum[0] + wsum[1] + wsum[2] + wsum[3];
        atomicAdd(acc, s);
        __threadfence();
        unsigned t = atomicAdd(cnt, 1u);
        if (t == (unsigned)(NBLOCKS - 1)) {
            float tot = atomicAdd(acc, 0.0f);  // atomic read of final total
            out[0] = 1.0f - tot / NOUT_TOTAL;
        }
    }
}

extern "C" void kernel_launch(void* const* d_in, const int* in_sizes, int n_in,
                              void* d_out, int out_size, void* d_ws, size_t ws_size,
                              hipStream_t stream) {
    const float* x = (const float*)d_in[0];
    const float* y = (const float*)d_in[1];
    float* out = (float*)d_out;
    float* acc = (float*)d_ws;                    // ws[0]: f32 accumulator
    unsigned int* cnt = (unsigned int*)d_ws + 1;  // ws[1]: block ticket counter

    // d_ws is re-poisoned (0xAA) before every launch — zero acc + counter.
    hipMemsetAsync(d_ws, 0, 8, stream);

    dim3 grid(NTX, NTY, NCH);
    ssim_main<<<grid, dim3(256), 0, stream>>>(x, y, acc, cnt, out);
}

// Round 4
// 340.887 us; speedup vs baseline: 2.3033x; 1.8956x over previous
//
#include <hip/hip_runtime.h>
#include <hip/hip_fp16.h>
#include <math.h>

// Problem constants (setup_inputs fixed: 1x3x2048x2048 fp32)
#define HH    2048
#define WW    2048
#define NCH   3
#define NOUT  2038          // 2048 - 10 (VALID 11-tap twice)
#define OWID  64            // output tile width
#define OHGT  32            // output tile height
#define IHGT  42            // OHGT + 10 (h-blurred rows needed)
#define SH    72            // LDS row stride in halves: 144B = 8B-aligned rows, ≡4 banks mod 32
#define NTX   32            // ceil(2038/64)
#define NTY   64            // ceil(2038/32)
#define NBLOCKS (NTX*NTY*NCH)
#define NOUT_TOTAL 12460332.0f   // 3 * 2038 * 2038

// SSIM per-pixel term. Scalar args, compile-time indices only at call sites —
// runtime pointer selection of register arrays caused scratch demotion (R2).
__device__ __forceinline__ float ssim_term(float mu1, float mu2,
                                           float b11, float b22, float b12) {
    const float c1v = 1e-4f, c2v = 9e-4f;
    float mu1sq = mu1 * mu1;
    float mu2sq = mu2 * mu2;
    float mu12  = mu1 * mu2;
    float s11 = b11 - mu1sq;
    float s22 = b22 - mu2sq;
    float s12 = b12 - mu12;
    float csn = 2.f * s12 + c2v;
    float csd = s11 + s22 + c2v;
    float ln  = 2.f * mu12 + c1v;
    float ld  = mu1sq + mu2sq + c1v;
    return (csn * ln) / (csd * ld);
}

// __launch_bounds__(256,2): with (256,4) the backend capped VGPRs at 64 and
// spilled ~90 live floats -> 357 MB scratch writes, 558 us (R3). (256,2)
// measured 88 VGPRs / zero spill in R1. Do not raise the 2nd arg.
__global__ __launch_bounds__(256, 2)
void ssim_main(const float* __restrict__ x, const float* __restrict__ y,
               float* __restrict__ acc, unsigned int* __restrict__ cnt,
               float* __restrict__ out) {
    // 5 h-blurred quantities (mu1,mu2,xx,yy,xy) in fp16: 5*42*72*2 = 30.2 KB
    __shared__ __half hb[5][IHGT][SH];
    __shared__ float wsum[4];

    const int tid = threadIdx.x;
    const int gx0 = blockIdx.x * OWID;
    const int gy0 = blockIdx.y * OHGT;
    const float* xb = x + (size_t)blockIdx.z * HH * WW;
    const float* yb = y + (size_t)blockIdx.z * HH * WW;

    // Gaussian weights (11 taps, sigma 1.5), normalized — matches jnp f32
    float w[11];
    {
        float s = 0.f;
        #pragma unroll
        for (int i = 0; i < 11; ++i) {
            float d = (float)(i - 5);
            w[i] = expf(-d * d / 4.5f);
            s += w[i];
        }
        float inv = 1.f / s;
        #pragma unroll
        for (int i = 0; i < 11; ++i) w[i] *= inv;
    }

    // ---- Stage B: horizontal blur, reading input windows straight from
    // global (float4; same-wave 4x overlap hits L1). Unit = (row, 4 cols).
    // Element-wise copies from float4 temps (NOT pointer-cast indexing) so
    // SROA keeps everything in VGPRs. ----
    for (int u = tid; u < IHGT * (OWID / 4); u += 256) {
        int r  = u >> 4;
        int c0 = (u & 15) * 4;
        int gy = gy0 + r; if (gy > HH - 1) gy = HH - 1;
        const float* xr = xb + (size_t)gy * WW;
        const float* yr = yb + (size_t)gy * WW;
        int gxc = gx0 + c0;

        float xv[16], yv[16];
        if (gxc + 16 <= WW) {
            float4 x0 = *(const float4*)(xr + gxc);
            float4 x1 = *(const float4*)(xr + gxc + 4);
            float4 x2 = *(const float4*)(xr + gxc + 8);
            float4 x3 = *(const float4*)(xr + gxc + 12);
            float4 y0 = *(const float4*)(yr + gxc);
            float4 y1 = *(const float4*)(yr + gxc + 4);
            float4 y2 = *(const float4*)(yr + gxc + 8);
            float4 y3 = *(const float4*)(yr + gxc + 12);
            xv[0]=x0.x; xv[1]=x0.y; xv[2]=x0.z; xv[3]=x0.w;
            xv[4]=x1.x; xv[5]=x1.y; xv[6]=x1.z; xv[7]=x1.w;
            xv[8]=x2.x; xv[9]=x2.y; xv[10]=x2.z; xv[11]=x2.w;
            xv[12]=x3.x; xv[13]=x3.y; xv[14]=x3.z; xv[15]=x3.w;
            yv[0]=y0.x; yv[1]=y0.y; yv[2]=y0.z; yv[3]=y0.w;
            yv[4]=y1.x; yv[5]=y1.y; yv[6]=y1.z; yv[7]=y1.w;
            yv[8]=y2.x; yv[9]=y2.y; yv[10]=y2.z; yv[11]=y2.w;
            yv[12]=y3.x; yv[13]=y3.y; yv[14]=y3.z; yv[15]=y3.w;
        } else {  // right-edge clamp (last block column only; clamped values
                  // feed only guarded outputs)
            #pragma unroll
            for (int t = 0; t < 16; ++t) {
                int gc = gxc + t; if (gc > WW - 1) gc = WW - 1;
                xv[t] = xr[gc]; yv[t] = yr[gc];
            }
        }

        float xx[14], yy2[14], xy[14];
        #pragma unroll
        for (int t = 0; t < 14; ++t) {
            xx[t]  = xv[t] * xv[t];
            yy2[t] = yv[t] * yv[t];
            xy[t]  = xv[t] * yv[t];
        }
        float h[5][4] = {};
        #pragma unroll
        for (int k = 0; k < 11; ++k) {
            #pragma unroll
            for (int j = 0; j < 4; ++j) {
                h[0][j] = fmaf(w[k], xv[j + k],  h[0][j]);
                h[1][j] = fmaf(w[k], yv[j + k],  h[1][j]);
                h[2][j] = fmaf(w[k], xx[j + k],  h[2][j]);
                h[3][j] = fmaf(w[k], yy2[j + k], h[3][j]);
                h[4][j] = fmaf(w[k], xy[j + k],  h[4][j]);
            }
        }
        #pragma unroll
        for (int q = 0; q < 5; ++q) {
            // 8B-aligned (SH*2=144B rows, c0*2 multiple of 8) -> ds_write_b64
            *(__half2*)&hb[q][r][c0]     = __floats2half2_rn(h[q][0], h[q][1]);
            *(__half2*)&hb[q][r][c0 + 2] = __floats2half2_rn(h[q][2], h[q][3]);
        }
    }
    __syncthreads();

    // ---- Stage C: vertical blur, 4 cols x 2 rows per thread (ds_read_b64,
    // 12-row window shared between the two output rows) + SSIM + partial sum ----
    float partial = 0.f;
    {
        const int c0 = (tid & 15) * 4;
        const int r0 = (tid >> 4) * 2;
        const __half* hp = &hb[0][r0][c0];
        float a0[5][4] = {}, a1[5][4] = {};
        #pragma unroll
        for (int j = 0; j < 12; ++j) {
            float v[5][4];
            #pragma unroll
            for (int q = 0; q < 5; ++q) {
                const __half* p = hp + q * (IHGT * SH) + j * SH;
                float2 raw = *(const float2*)p;          // one ds_read_b64
                float2 lo = __half22float2(*(const __half2*)&raw.x);
                float2 hi = __half22float2(*(const __half2*)&raw.y);
                v[q][0] = lo.x; v[q][1] = lo.y; v[q][2] = hi.x; v[q][3] = hi.y;
            }
            if (j < 11) {
                #pragma unroll
                for (int q = 0; q < 5; ++q)
                    #pragma unroll
                    for (int c = 0; c < 4; ++c)
                        a0[q][c] = fmaf(w[j], v[q][c], a0[q][c]);
            }
            if (j >= 1) {
                #pragma unroll
                for (int q = 0; q < 5; ++q)
                    #pragma unroll
                    for (int c = 0; c < 4; ++c)
                        a1[q][c] = fmaf(w[j - 1], v[q][c], a1[q][c]);
            }
        }
        const bool row0ok = (gy0 + r0)     < NOUT;
        const bool row1ok = (gy0 + r0 + 1) < NOUT;
        #pragma unroll
        for (int c = 0; c < 4; ++c) {
            bool colok = (gx0 + c0 + c) < NOUT;
            if (row0ok && colok)
                partial += ssim_term(a0[0][c], a0[1][c], a0[2][c], a0[3][c], a0[4][c]);
            if (row1ok && colok)
                partial += ssim_term(a1[0][c], a1[1][c], a1[2][c], a1[3][c], a1[4][c]);
        }
    }

    // ---- Reduction: wave shuffle -> block -> one atomic; last block finalizes ----
    #pragma unroll
    for (int off = 32; off > 0; off >>= 1)
        partial += __shfl_down(partial, off, 64);
    if ((tid & 63) == 0) wsum[tid >> 6] = partial;
    __syncthreads();
    if (tid == 0) {
        float s = wsum[0] + wsum[1] + wsum[2] + wsum[3];
        atomicAdd(acc, s);
        __threadfence();
        unsigned t = atomicAdd(cnt, 1u);
        if (t == (unsigned)(NBLOCKS - 1)) {
            float tot = atomicAdd(acc, 0.0f);  // atomic read of final total
            out[0] = 1.0f - tot / NOUT_TOTAL;
        }
    }
}

extern "C" void kernel_launch(void* const* d_in, const int* in_sizes, int n_in,
                              void* d_out, int out_size, void* d_ws, size_t ws_size,
                              hipStream_t stream) {
    const float* x = (const float*)d_in[0];
    const float* y = (const float*)d_in[1];
    float* out = (float*)d_out;
    float* acc = (float*)d_ws;                    // ws[0]: f32 accumulator
    unsigned int* cnt = (unsigned int*)d_ws + 1;  // ws[1]: block ticket counter

    // d_ws is re-poisoned (0xAA) before every launch — zero acc + counter.
    hipMemsetAsync(d_ws, 0, 8, stream);

    dim3 grid(NTX, NTY, NCH);
    ssim_main<<<grid, dim3(256), 0, stream>>>(x, y, acc, cnt, out);
}

// Round 5
// 324.871 us; speedup vs baseline: 2.4169x; 1.0493x over previous
//
#include <hip/hip_runtime.h>
#include <hip/hip_fp16.h>
#include <math.h>

// Problem constants (setup_inputs fixed: 1x3x2048x2048 fp32)
#define HH    2048
#define WW    2048
#define NCH   3
#define NOUT  2038          // 2048 - 10 (VALID 11-tap twice)
#define OWID  64            // output tile width
#define OHGT  32            // output tile height
#define IHGT  42            // OHGT + 10
#define IWID  74            // OWID + 10
#define SW    76            // input LDS stride (halves): 152B rows, 8B-aligned
#define SWH   64            // hb LDS stride (halves): 128B rows
#define NTX   32            // ceil(2038/64)
#define NTY   64            // ceil(2038/32)
#define NBLOCKS (NTX*NTY*NCH)
#define NOUT_TOTAL 12460332.0f   // 3 * 2038 * 2038

// SSIM per-pixel term. Scalar args, compile-time indices only at call sites —
// runtime pointer selection of register arrays caused scratch demotion (R2).
__device__ __forceinline__ float ssim_term(float mu1, float mu2,
                                           float b11, float b22, float b12) {
    const float c1v = 1e-4f, c2v = 9e-4f;
    float mu1sq = mu1 * mu1;
    float mu2sq = mu2 * mu2;
    float mu12  = mu1 * mu2;
    float s11 = b11 - mu1sq;
    float s22 = b22 - mu2sq;
    float s12 = b12 - mu12;
    float csn = 2.f * s12 + c2v;
    float csd = s11 + s22 + c2v;
    float ln  = 2.f * mu12 + c1v;
    float ld  = mu1sq + mu2sq + c1v;
    return (csn * ln) / (csd * ld);
}

// Unpack 4 fp16 (read as one b64) into 4 floats at compile-time offsets.
__device__ __forceinline__ void unpack4(float2 raw, float* dst) {
    float2 lo = __half22float2(*(const __half2*)&raw.x);
    float2 hi = __half22float2(*(const __half2*)&raw.y);
    dst[0] = lo.x; dst[1] = lo.y; dst[2] = hi.x; dst[3] = hi.y;
}

// __launch_bounds__(256,2): (256,4) capped VGPRs at 64 -> massive spill (R3:
// 357 MB scratch writes). (256,2) -> 96 VGPRs, zero spill (R4). Keep.
__global__ __launch_bounds__(256, 2)
void ssim_main(const float* __restrict__ x, const float* __restrict__ y,
               float* __restrict__ acc, unsigned int* __restrict__ cnt,
               float* __restrict__ out) {
    // fp16 staged inputs (12.8 KB) + fp16 h-blurred quantities (26.9 KB)
    // = 39.7 KB total -> 4 blocks/CU (R1's fp32 64.5 KB gave only 2).
    __shared__ __half sx[IHGT][SW];
    __shared__ __half sy[IHGT][SW];
    __shared__ __half hb[5][IHGT][SWH];
    __shared__ float wsum[4];

    const int tid = threadIdx.x;
    const int gx0 = blockIdx.x * OWID;
    const int gy0 = blockIdx.y * OHGT;
    const float* xb = x + (size_t)blockIdx.z * HH * WW;
    const float* yb = y + (size_t)blockIdx.z * HH * WW;

    // Gaussian weights (11 taps, sigma 1.5), normalized — matches jnp f32
    float w[11];
    {
        float s = 0.f;
        #pragma unroll
        for (int i = 0; i < 11; ++i) {
            float d = (float)(i - 5);
            w[i] = expf(-d * d / 4.5f);
            s += w[i];
        }
        float inv = 1.f / s;
        #pragma unroll
        for (int i = 0; i < 11; ++i) w[i] *= inv;
    }

    // ---- Stage A: global -> LDS (fp16), one coalesced float4 load per 4 px.
    // Direct-global stage B (R4) was latency-bound: 21 VMEM/thread feeding
    // FMAs directly -> 263 us at 21% VALUBusy. Stage through LDS instead. ----
    for (int u = tid; u < IHGT * 19; u += 256) {
        int r  = u / 19;                 // compiler magic-mul
        int c0 = (u - r * 19) * 4;       // 0..72 (cols 74,75 written, unused)
        int gy = gy0 + r; if (gy > HH - 1) gy = HH - 1;
        const float* xr = xb + (size_t)gy * WW;
        const float* yr = yb + (size_t)gy * WW;
        int gxc = gx0 + c0;
        float4 xf, yf;
        if (gxc + 4 <= WW) {
            xf = *(const float4*)(xr + gxc);
            yf = *(const float4*)(yr + gxc);
        } else {  // right-edge clamp (last tile column only; feeds only
                  // guarded outputs)
            int g0 = gxc     < WW ? gxc     : WW - 1;
            int g1 = gxc + 1 < WW ? gxc + 1 : WW - 1;
            int g2 = gxc + 2 < WW ? gxc + 2 : WW - 1;
            int g3 = gxc + 3 < WW ? gxc + 3 : WW - 1;
            xf = make_float4(xr[g0], xr[g1], xr[g2], xr[g3]);
            yf = make_float4(yr[g0], yr[g1], yr[g2], yr[g3]);
        }
        *(__half2*)&sx[r][c0]     = __floats2half2_rn(xf.x, xf.y);
        *(__half2*)&sx[r][c0 + 2] = __floats2half2_rn(xf.z, xf.w);
        *(__half2*)&sy[r][c0]     = __floats2half2_rn(yf.x, yf.y);
        *(__half2*)&sy[r][c0 + 2] = __floats2half2_rn(yf.z, yf.w);
    }
    __syncthreads();

    // ---- Stage B: horizontal blur from LDS, 4 output cols per unit.
    // 8 ds_read_b64 per unit (conflict-free: 16-lane group covers all 32
    // banks; stride 76 halves = 38 words). ----
    for (int u = tid; u < IHGT * 16; u += 256) {
        int r  = u >> 4;
        int c0 = (u & 15) * 4;
        float xv[16], yv[16];
        unpack4(*(const float2*)&sx[r][c0],      &xv[0]);
        unpack4(*(const float2*)&sx[r][c0 + 4],  &xv[4]);
        unpack4(*(const float2*)&sx[r][c0 + 8],  &xv[8]);
        unpack4(*(const float2*)&sx[r][c0 + 12], &xv[12]);
        unpack4(*(const float2*)&sy[r][c0],      &yv[0]);
        unpack4(*(const float2*)&sy[r][c0 + 4],  &yv[4]);
        unpack4(*(const float2*)&sy[r][c0 + 8],  &yv[8]);
        unpack4(*(const float2*)&sy[r][c0 + 12], &yv[12]);

        float xx[14], yy2[14], xy[14];
        #pragma unroll
        for (int t = 0; t < 14; ++t) {
            xx[t]  = xv[t] * xv[t];
            yy2[t] = yv[t] * yv[t];
            xy[t]  = xv[t] * yv[t];
        }
        float h[5][4] = {};
        #pragma unroll
        for (int k = 0; k < 11; ++k) {
            #pragma unroll
            for (int j = 0; j < 4; ++j) {
                h[0][j] = fmaf(w[k], xv[j + k],  h[0][j]);
                h[1][j] = fmaf(w[k], yv[j + k],  h[1][j]);
                h[2][j] = fmaf(w[k], xx[j + k],  h[2][j]);
                h[3][j] = fmaf(w[k], yy2[j + k], h[3][j]);
                h[4][j] = fmaf(w[k], xy[j + k],  h[4][j]);
            }
        }
        #pragma unroll
        for (int q = 0; q < 5; ++q) {
            *(__half2*)&hb[q][r][c0]     = __floats2half2_rn(h[q][0], h[q][1]);
            *(__half2*)&hb[q][r][c0 + 2] = __floats2half2_rn(h[q][2], h[q][3]);
        }
    }
    __syncthreads();

    // ---- Stage C: vertical blur, 4 cols x 2 rows per thread (ds_read_b64,
    // 12-row window shared between the two output rows) + SSIM + partial sum ----
    float partial = 0.f;
    {
        const int c0 = (tid & 15) * 4;
        const int r0 = (tid >> 4) * 2;
        const __half* hp = &hb[0][r0][c0];
        float a0[5][4] = {}, a1[5][4] = {};
        #pragma unroll
        for (int j = 0; j < 12; ++j) {
            float v[5][4];
            #pragma unroll
            for (int q = 0; q < 5; ++q) {
                const __half* p = hp + q * (IHGT * SWH) + j * SWH;
                unpack4(*(const float2*)p, &v[q][0]);
            }
            if (j < 11) {
                #pragma unroll
                for (int q = 0; q < 5; ++q)
                    #pragma unroll
                    for (int c = 0; c < 4; ++c)
                        a0[q][c] = fmaf(w[j], v[q][c], a0[q][c]);
            }
            if (j >= 1) {
                #pragma unroll
                for (int q = 0; q < 5; ++q)
                    #pragma unroll
                    for (int c = 0; c < 4; ++c)
                        a1[q][c] = fmaf(w[j - 1], v[q][c], a1[q][c]);
            }
        }
        const bool row0ok = (gy0 + r0)     < NOUT;
        const bool row1ok = (gy0 + r0 + 1) < NOUT;
        #pragma unroll
        for (int c = 0; c < 4; ++c) {
            bool colok = (gx0 + c0 + c) < NOUT;
            if (row0ok && colok)
                partial += ssim_term(a0[0][c], a0[1][c], a0[2][c], a0[3][c], a0[4][c]);
            if (row1ok && colok)
                partial += ssim_term(a1[0][c], a1[1][c], a1[2][c], a1[3][c], a1[4][c]);
        }
    }

    // ---- Reduction: wave shuffle -> block -> one atomic; last block finalizes ----
    #pragma unroll
    for (int off = 32; off > 0; off >>= 1)
        partial += __shfl_down(partial, off, 64);
    if ((tid & 63) == 0) wsum[tid >> 6] = partial;
    __syncthreads();
    if (tid == 0) {
        float s = wsum[0] + wsum[1] + wsum[2] + wsum[3];
        atomicAdd(acc, s);
        __threadfence();
        unsigned t = atomicAdd(cnt, 1u);
        if (t == (unsigned)(NBLOCKS - 1)) {
            float tot = atomicAdd(acc, 0.0f);  // atomic read of final total
            out[0] = 1.0f - tot / NOUT_TOTAL;
        }
    }
}

extern "C" void kernel_launch(void* const* d_in, const int* in_sizes, int n_in,
                              void* d_out, int out_size, void* d_ws, size_t ws_size,
                              hipStream_t stream) {
    const float* x = (const float*)d_in[0];
    const float* y = (const float*)d_in[1];
    float* out = (float*)d_out;
    float* acc = (float*)d_ws;                    // ws[0]: f32 accumulator
    unsigned int* cnt = (unsigned int*)d_ws + 1;  // ws[1]: block ticket counter

    // d_ws is re-poisoned (0xAA) before every launch — zero acc + counter.
    hipMemsetAsync(d_ws, 0, 8, stream);

    dim3 grid(NTX, NTY, NCH);
    ssim_main<<<grid, dim3(256), 0, stream>>>(x, y, acc, cnt, out);
}

// Round 6
// 212.420 us; speedup vs baseline: 3.6963x; 1.5294x over previous
//
#include <hip/hip_runtime.h>
#include <math.h>

// Problem constants (setup_inputs fixed: 1x3x2048x2048 fp32)
#define HH    2048
#define WW    2048
#define NCH   3
#define NOUT  2038          // 2048 - 10 (VALID 11-tap twice)
#define OWID  64            // output tile width
#define OHGT  24            // output tile height (R1's proven shape)
#define IWID  74            // OWID + 10
#define IHGT  34            // OHGT + 10
#define SXW   76            // input LDS stride (floats): 16B-aligned rows
#define HBW   64            // hb LDS stride (floats)
#define NTX   32            // ceil(2038/64)
#define NTY   85            // ceil(2038/24)
#define NBLOCKS (NTX*NTY*NCH)   // 8160
#define NOUT_TOTAL 12460332.0f  // 3 * 2038 * 2038

// SSIM per-pixel term. Scalar args, compile-time indices at call sites only
// (runtime pointer-select of register arrays caused scratch demotion in R2:
// 664 MB spill writes). rcpf: denominators >= 9e-4, rel err ~1e-6 vs 2e-2
// threshold.
__device__ __forceinline__ float ssim_term(float mu1, float mu2,
                                           float b11, float b22, float b12) {
    const float c1v = 1e-4f, c2v = 9e-4f;
    float mu1sq = mu1 * mu1;
    float mu2sq = mu2 * mu2;
    float mu12  = mu1 * mu2;
    float s11 = b11 - mu1sq;
    float s22 = b22 - mu2sq;
    float s12 = b12 - mu12;
    float csn = 2.f * s12 + c2v;
    float csd = s11 + s22 + c2v;
    float ln  = 2.f * mu12 + c1v;
    float ld  = mu1sq + mu2sq + c1v;
    return (csn * ln) * __builtin_amdgcn_rcpf(csd * ld);
}

// fp32 end-to-end: R5's fp16 LDS experiment REGRESSED (240 vs R1's 168 us) —
// cvt chains after every LDS read + b64 instead of b128 cost more in per-wave
// ILP than the extra occupancy bought. Keep R1's fp32/b128/scalar-batch form.
// __launch_bounds__(256,2): (256,4) capped VGPRs at 64 -> massive spill (R3).
__global__ __launch_bounds__(256, 2)
void ssim_main(const float* __restrict__ x, const float* __restrict__ y,
               float* __restrict__ partials) {
    __shared__ float sx[IHGT][SXW];       // 10.3 KB
    __shared__ float sy[IHGT][SXW];       // 10.3 KB
    __shared__ float hb[5][IHGT][HBW];    // 43.5 KB  (total 64.2 KB, 2 blk/CU)
    __shared__ float wsum[4];

    const int tid = threadIdx.x;
    const int gx0 = blockIdx.x * OWID;
    const int gy0 = blockIdx.y * OHGT;
    const float* xb = x + (size_t)blockIdx.z * HH * WW;
    const float* yb = y + (size_t)blockIdx.z * HH * WW;

    // Gaussian weights (11 taps, sigma 1.5), normalized — matches jnp f32
    float w[11];
    {
        float s = 0.f;
        #pragma unroll
        for (int i = 0; i < 11; ++i) {
            float d = (float)(i - 5);
            w[i] = expf(-d * d / 4.5f);
            s += w[i];
        }
        float inv = 1.f / s;
        #pragma unroll
        for (int i = 0; i < 11; ++i) w[i] *= inv;
    }

    // ---- Stage A: global -> LDS fp32, float4 loads (6 VMEM/thread vs R1's
    // ~20 scalar). Edge-clamped values feed only guarded outputs. ----
    for (int u = tid; u < IHGT * 19; u += 256) {
        int r  = u / 19;                 // compiler magic-mul
        int c0 = (u - r * 19) * 4;       // 0..72 (cols 74,75 unused)
        int gy = gy0 + r; if (gy > HH - 1) gy = HH - 1;
        const float* xr = xb + (size_t)gy * WW;
        const float* yr = yb + (size_t)gy * WW;
        int gxc = gx0 + c0;
        float4 xf, yf;
        if (gxc + 4 <= WW) {
            xf = *(const float4*)(xr + gxc);
            yf = *(const float4*)(yr + gxc);
        } else {
            int g0 = gxc     < WW ? gxc     : WW - 1;
            int g1 = gxc + 1 < WW ? gxc + 1 : WW - 1;
            int g2 = gxc + 2 < WW ? gxc + 2 : WW - 1;
            int g3 = gxc + 3 < WW ? gxc + 3 : WW - 1;
            xf = make_float4(xr[g0], xr[g1], xr[g2], xr[g3]);
            yf = make_float4(yr[g0], yr[g1], yr[g2], yr[g3]);
        }
        *(float4*)&sx[r][c0] = xf;       // 16B-aligned (SXW=76, c0%4==0)
        *(float4*)&sy[r][c0] = yf;
    }
    __syncthreads();

    // ---- Stage B: horizontal blur, 4 output cols per unit, b128 LDS reads,
    // explicit element copies (SROA-safe, R4-verified no spill). ----
    for (int u = tid; u < IHGT * 16; u += 256) {
        int r  = u >> 4;
        int c0 = (u & 15) * 4;
        float xv[16], yv[16];
        {
            float4 x0 = *(const float4*)&sx[r][c0];
            float4 x1 = *(const float4*)&sx[r][c0 + 4];
            float4 x2 = *(const float4*)&sx[r][c0 + 8];
            float4 x3 = *(const float4*)&sx[r][c0 + 12];
            float4 y0 = *(const float4*)&sy[r][c0];
            float4 y1 = *(const float4*)&sy[r][c0 + 4];
            float4 y2 = *(const float4*)&sy[r][c0 + 8];
            float4 y3 = *(const float4*)&sy[r][c0 + 12];
            xv[0]=x0.x; xv[1]=x0.y; xv[2]=x0.z; xv[3]=x0.w;
            xv[4]=x1.x; xv[5]=x1.y; xv[6]=x1.z; xv[7]=x1.w;
            xv[8]=x2.x; xv[9]=x2.y; xv[10]=x2.z; xv[11]=x2.w;
            xv[12]=x3.x; xv[13]=x3.y; xv[14]=x3.z; xv[15]=x3.w;
            yv[0]=y0.x; yv[1]=y0.y; yv[2]=y0.z; yv[3]=y0.w;
            yv[4]=y1.x; yv[5]=y1.y; yv[6]=y1.z; yv[7]=y1.w;
            yv[8]=y2.x; yv[9]=y2.y; yv[10]=y2.z; yv[11]=y2.w;
            yv[12]=y3.x; yv[13]=y3.y; yv[14]=y3.z; yv[15]=y3.w;
        }
        float xx[14], yy2[14], xy[14];
        #pragma unroll
        for (int t = 0; t < 14; ++t) {
            xx[t]  = xv[t] * xv[t];
            yy2[t] = yv[t] * yv[t];
            xy[t]  = xv[t] * yv[t];
        }
        float h[5][4] = {};
        #pragma unroll
        for (int k = 0; k < 11; ++k) {
            #pragma unroll
            for (int j = 0; j < 4; ++j) {
                h[0][j] = fmaf(w[k], xv[j + k],  h[0][j]);
                h[1][j] = fmaf(w[k], yv[j + k],  h[1][j]);
                h[2][j] = fmaf(w[k], xx[j + k],  h[2][j]);
                h[3][j] = fmaf(w[k], yy2[j + k], h[3][j]);
                h[4][j] = fmaf(w[k], xy[j + k],  h[4][j]);
            }
        }
        #pragma unroll
        for (int q = 0; q < 5; ++q)
            *(float4*)&hb[q][r][c0] = make_float4(h[q][0], h[q][1], h[q][2], h[q][3]);
    }
    __syncthreads();

    // ---- Stage C: vertical blur, 1 col x 6 rows per thread. 80 independent
    // scalar LDS reads batched up front, then a pure FMA burn — R1's
    // best-measured ILP pattern. ----
    float partial = 0.f;
    {
        const int col = tid & 63;
        const int rg  = tid >> 6;     // 0..3
        const int r0  = rg * 6;       // rows r0..r0+5 of the 24-row tile
        float v1[16], v2[16], v11[16], v22[16], v12[16];
        #pragma unroll
        for (int j = 0; j < 16; ++j) {
            v1[j]  = hb[0][r0 + j][col];
            v2[j]  = hb[1][r0 + j][col];
            v11[j] = hb[2][r0 + j][col];
            v22[j] = hb[3][r0 + j][col];
            v12[j] = hb[4][r0 + j][col];
        }
        const int ocol = gx0 + col;
        #pragma unroll
        for (int i = 0; i < 6; ++i) {
            float mu1 = 0, mu2 = 0, b11 = 0, b22 = 0, b12 = 0;
            #pragma unroll
            for (int k = 0; k < 11; ++k) {
                mu1 = fmaf(w[k], v1[i + k], mu1);
                mu2 = fmaf(w[k], v2[i + k], mu2);
                b11 = fmaf(w[k], v11[i + k], b11);
                b22 = fmaf(w[k], v22[i + k], b22);
                b12 = fmaf(w[k], v12[i + k], b12);
            }
            int orow = gy0 + r0 + i;
            if (orow < NOUT && ocol < NOUT)
                partial += ssim_term(mu1, mu2, b11, b22, b12);
        }
    }

    // ---- Reduction: wave shuffle -> block -> one plain store per block.
    // No atomics, no init needed (every slot overwritten every launch). ----
    #pragma unroll
    for (int off = 32; off > 0; off >>= 1)
        partial += __shfl_down(partial, off, 64);
    if ((tid & 63) == 0) wsum[tid >> 6] = partial;
    __syncthreads();
    if (tid == 0) {
        int bid = (blockIdx.z * gridDim.y + blockIdx.y) * gridDim.x + blockIdx.x;
        partials[bid] = wsum[0] + wsum[1] + wsum[2] + wsum[3];
    }
}

__global__ __launch_bounds__(256)
void ssim_finalize(const float* __restrict__ partials, float* __restrict__ out) {
    __shared__ float ws[4];
    float s = 0.f;
    for (int i = threadIdx.x; i < NBLOCKS; i += 256) s += partials[i];
    #pragma unroll
    for (int off = 32; off > 0; off >>= 1)
        s += __shfl_down(s, off, 64);
    if ((threadIdx.x & 63) == 0) ws[threadIdx.x >> 6] = s;
    __syncthreads();
    if (threadIdx.x == 0)
        out[0] = 1.f - (ws[0] + ws[1] + ws[2] + ws[3]) / NOUT_TOTAL;
}

extern "C" void kernel_launch(void* const* d_in, const int* in_sizes, int n_in,
                              void* d_out, int out_size, void* d_ws, size_t ws_size,
                              hipStream_t stream) {
    const float* x = (const float*)d_in[0];
    const float* y = (const float*)d_in[1];
    float* out = (float*)d_out;
    float* partials = (float*)d_ws;   // NBLOCKS floats = 32.6 KB of scratch

    dim3 grid(NTX, NTY, NCH);
    ssim_main<<<grid, dim3(256), 0, stream>>>(x, y, partials);
    ssim_finalize<<<1, 256, 0, stream>>>(partials, out);
}

// Round 7
// 185.218 us; speedup vs baseline: 4.2392x; 1.1469x over previous
//
#include <hip/hip_runtime.h>
#include <math.h>

typedef float f32x2 __attribute__((ext_vector_type(2)));
typedef float f32x4 __attribute__((ext_vector_type(4)));

// Problem constants (setup_inputs fixed: 1x3x2048x2048 fp32)
#define HH    2048
#define WW    2048
#define NCH   3
#define NOUT  2038          // 2048 - 10 (VALID 11-tap twice)
#define OWID  64            // output tile width
#define OHGT  16            // output tile height (shrunk 24->16 for 3 blk/CU)
#define IHGT  26            // OHGT + 10
#define SWP   76            // sxy stride in (x,y) pairs: 608B rows ≡ 24 banks
#define HAW   66            // hbA/hbB stride in pairs: 528B rows ≡ 4 banks
#define HCW   68            // hbC stride in floats: 272B rows ≡ 4 banks
#define NTX   32            // ceil(2038/64)
#define NTY   128           // ceil(2038/16)
#define NBLOCKS (NTX*NTY*NCH)   // 12288
#define NOUT_TOTAL 12460332.0f  // 3 * 2038 * 2038

// SSIM per-pixel term. Scalar args, compile-time indices at call sites only
// (runtime pointer-select of register arrays caused scratch demotion in R2:
// 664 MB spill writes). rcpf: denominators >= 9e-4, rel err ~1e-6 vs 2e-2
// threshold.
__device__ __forceinline__ float ssim_term(float mu1, float mu2,
                                           float b11, float b22, float b12) {
    const float c1v = 1e-4f, c2v = 9e-4f;
    float mu1sq = mu1 * mu1;
    float mu2sq = mu2 * mu2;
    float mu12  = mu1 * mu2;
    float s11 = b11 - mu1sq;
    float s22 = b22 - mu2sq;
    float s12 = b12 - mu12;
    float csn = 2.f * s12 + c2v;
    float csd = s11 + s22 + c2v;
    float ln  = 2.f * mu12 + c1v;
    float ld  = mu1sq + mu2sq + c1v;
    return (csn * ln) * __builtin_amdgcn_rcpf(csd * ld);
}

// fp32 end-to-end (R5's fp16 LDS regressed: cvt chains + b64 reads cost more
// ILP than occupancy gained). Packed-pair layout targets v_pk_fma_f32:
// 3 issue slots per blur tap instead of 5.
// __launch_bounds__(256,2): (256,4) capped VGPRs at 64 -> massive spill (R3).
__global__ __launch_bounds__(256, 2)
void ssim_main(const float* __restrict__ x, const float* __restrict__ y,
               float* __restrict__ partials) {
    __shared__ f32x2 sxy[IHGT][SWP];     // interleaved (x,y): 15.8 KB
    __shared__ f32x2 hbA[IHGT][HAW];     // (mu1,mu2) h-blur: 13.7 KB
    __shared__ f32x2 hbB[IHGT][HAW];     // (xx,yy)  h-blur: 13.7 KB
    __shared__ float hbC[IHGT][HCW];     // xy       h-blur:  7.1 KB
    __shared__ float wsum[4];            // total 50.3 KB -> 3 blocks/CU

    const int tid = threadIdx.x;
    const int gx0 = blockIdx.x * OWID;
    const int gy0 = blockIdx.y * OHGT;
    const float* xb = x + (size_t)blockIdx.z * HH * WW;
    const float* yb = y + (size_t)blockIdx.z * HH * WW;

    // Gaussian weights (11 taps, sigma 1.5), normalized — matches jnp f32
    float w[11];
    {
        float s = 0.f;
        #pragma unroll
        for (int i = 0; i < 11; ++i) {
            float d = (float)(i - 5);
            w[i] = expf(-d * d / 4.5f);
            s += w[i];
        }
        float inv = 1.f / s;
        #pragma unroll
        for (int i = 0; i < 11; ++i) w[i] *= inv;
    }

    // ---- Stage A: global -> LDS interleaved (x,y) pairs. float4 global
    // loads, 2x b128 LDS writes. Edge-clamped values feed only guarded
    // outputs. ----
    for (int u = tid; u < IHGT * 19; u += 256) {
        int r  = u / 19;                 // compiler magic-mul
        int c0 = (u - r * 19) * 4;       // pair cols 0..72 (74,75 unused)
        int gy = gy0 + r; if (gy > HH - 1) gy = HH - 1;
        const float* xr = xb + (size_t)gy * WW;
        const float* yr = yb + (size_t)gy * WW;
        int gxc = gx0 + c0;
        float4 xf, yf;
        if (gxc + 4 <= WW) {
            xf = *(const float4*)(xr + gxc);
            yf = *(const float4*)(yr + gxc);
        } else {
            int g0 = gxc     < WW ? gxc     : WW - 1;
            int g1 = gxc + 1 < WW ? gxc + 1 : WW - 1;
            int g2 = gxc + 2 < WW ? gxc + 2 : WW - 1;
            int g3 = gxc + 3 < WW ? gxc + 3 : WW - 1;
            xf = make_float4(xr[g0], xr[g1], xr[g2], xr[g3]);
            yf = make_float4(yr[g0], yr[g1], yr[g2], yr[g3]);
        }
        // 16B-aligned: row = 608B, c0 even
        *(f32x4*)&sxy[r][c0]     = (f32x4){xf.x, yf.x, xf.y, yf.y};
        *(f32x4*)&sxy[r][c0 + 2] = (f32x4){xf.z, yf.z, xf.w, yf.w};
    }
    __syncthreads();

    // ---- Stage B: horizontal blur, 4 output cols per unit. Per tap per col:
    // pk_fma(mu pair) + pk_fma(sq pair) + fma(xy) = 3 slots (was 5). ----
    for (int u = tid; u < IHGT * 16; u += 256) {
        int r  = u >> 4;
        int c0 = (u & 15) * 4;
        f32x2 p[16];
        #pragma unroll
        for (int t = 0; t < 8; ++t) {
            f32x4 raw = *(const f32x4*)&sxy[r][c0 + 2 * t];
            p[2 * t]     = (f32x2){raw.x, raw.y};
            p[2 * t + 1] = (f32x2){raw.z, raw.w};
        }
        f32x2 q[14]; float pr[14];
        #pragma unroll
        for (int t = 0; t < 14; ++t) {
            q[t]  = p[t] * p[t];         // v_pk_mul_f32: (x^2, y^2)
            pr[t] = p[t].x * p[t].y;     // x*y
        }
        f32x2 hA[4] = {}, hB[4] = {};
        float hC[4] = {};
        #pragma unroll
        for (int k = 0; k < 11; ++k) {
            f32x2 wk2 = (f32x2){w[k], w[k]};
            #pragma unroll
            for (int j = 0; j < 4; ++j) {
                hA[j] = __builtin_elementwise_fma(wk2, p[j + k], hA[j]);
                hB[j] = __builtin_elementwise_fma(wk2, q[j + k], hB[j]);
                hC[j] = fmaf(w[k], pr[j + k], hC[j]);
            }
        }
        // 16B-aligned stores (rows 528B / 272B, c0 mult of 4)
        *(f32x4*)&hbA[r][c0]     = (f32x4){hA[0].x, hA[0].y, hA[1].x, hA[1].y};
        *(f32x4*)&hbA[r][c0 + 2] = (f32x4){hA[2].x, hA[2].y, hA[3].x, hA[3].y};
        *(f32x4*)&hbB[r][c0]     = (f32x4){hB[0].x, hB[0].y, hB[1].x, hB[1].y};
        *(f32x4*)&hbB[r][c0 + 2] = (f32x4){hB[2].x, hB[2].y, hB[3].x, hB[3].y};
        *(float4*)&hbC[r][c0]    = make_float4(hC[0], hC[1], hC[2], hC[3]);
    }
    __syncthreads();

    // ---- Stage C: vertical blur, 1 col x 4 rows per thread. 42 batched LDS
    // reads (was 80), then pk_fma burn + SSIM. ----
    float partial = 0.f;
    {
        const int col = tid & 63;
        const int r0  = (tid >> 6) * 4;   // rows r0..r0+3 of the 16-row tile
        f32x2 vA[14], vB[14]; float vC[14];
        #pragma unroll
        for (int j = 0; j < 14; ++j) {
            vA[j] = hbA[r0 + j][col];     // ds_read_b64, contiguous lanes
            vB[j] = hbB[r0 + j][col];
            vC[j] = hbC[r0 + j][col];
        }
        const int ocol = gx0 + col;
        #pragma unroll
        for (int i = 0; i < 4; ++i) {
            f32x2 aA = {0.f, 0.f}, aB = {0.f, 0.f};
            float aC = 0.f;
            #pragma unroll
            for (int k = 0; k < 11; ++k) {
                f32x2 wk2 = (f32x2){w[k], w[k]};
                aA = __builtin_elementwise_fma(wk2, vA[i + k], aA);
                aB = __builtin_elementwise_fma(wk2, vB[i + k], aB);
                aC = fmaf(w[k], vC[i + k], aC);
            }
            int orow = gy0 + r0 + i;
            if (orow < NOUT && ocol < NOUT)
                partial += ssim_term(aA.x, aA.y, aB.x, aB.y, aC);
        }
    }

    // ---- Reduction: wave shuffle -> block -> one plain store per block. ----
    #pragma unroll
    for (int off = 32; off > 0; off >>= 1)
        partial += __shfl_down(partial, off, 64);
    if ((tid & 63) == 0) wsum[tid >> 6] = partial;
    __syncthreads();
    if (tid == 0) {
        int bid = (blockIdx.z * gridDim.y + blockIdx.y) * gridDim.x + blockIdx.x;
        partials[bid] = wsum[0] + wsum[1] + wsum[2] + wsum[3];
    }
}

__global__ __launch_bounds__(256)
void ssim_finalize(const float* __restrict__ partials, float* __restrict__ out) {
    __shared__ float ws[4];
    float s = 0.f;
    // NBLOCKS = 12288 = 3072 float4s; 12 vector loads per thread
    for (int i = threadIdx.x; i < NBLOCKS / 4; i += 256) {
        float4 v = ((const float4*)partials)[i];
        s += (v.x + v.y) + (v.z + v.w);
    }
    #pragma unroll
    for (int off = 32; off > 0; off >>= 1)
        s += __shfl_down(s, off, 64);
    if ((threadIdx.x & 63) == 0) ws[threadIdx.x >> 6] = s;
    __syncthreads();
    if (threadIdx.x == 0)
        out[0] = 1.f - (ws[0] + ws[1] + ws[2] + ws[3]) / NOUT_TOTAL;
}

extern "C" void kernel_launch(void* const* d_in, const int* in_sizes, int n_in,
                              void* d_out, int out_size, void* d_ws, size_t ws_size,
                              hipStream_t stream) {
    const float* x = (const float*)d_in[0];
    const float* y = (const float*)d_in[1];
    float* out = (float*)d_out;
    float* partials = (float*)d_ws;   // NBLOCKS floats = 48 KB of scratch

    dim3 grid(NTX, NTY, NCH);
    ssim_main<<<grid, dim3(256), 0, stream>>>(x, y, partials);
    ssim_finalize<<<1, 256, 0, stream>>>(partials, out);
}